// Round 6
// baseline (221.521 us; speedup 1.0000x reference)
//
#include <hip/hip_runtime.h>
#include <hip/hip_bf16.h>

typedef __attribute__((ext_vector_type(8))) short short8;
typedef __attribute__((ext_vector_type(4))) short short4v;
typedef __attribute__((ext_vector_type(4))) float f32x4;

__device__ __forceinline__ unsigned short f2bf(float f) {
    __hip_bfloat16 h = __float2bfloat16(f);
    unsigned short u;
    __builtin_memcpy(&u, &h, 2);
    return u;
}
// packed RNE f32->bf16 pairs: compiles to v_cvt_pk_bf16_f32
__device__ __forceinline__ short4v pack4bf(float a, float b, float c, float d) {
    union { __hip_bfloat162 h[2]; short4v s; } r;
    r.h[0] = __float22bfloat162_rn(make_float2(a, b));
    r.h[1] = __float22bfloat162_rn(make_float2(c, d));
    return r.s;
}

#define GLD16(gp, lp) __builtin_amdgcn_global_load_lds( \
    (const __attribute__((address_space(1))) void*)(gp), \
    (__attribute__((address_space(3))) void*)(lp), 16, 0, 0)

// counted-vmcnt barrier: retire current tile's loads, keep next tiles' in
// flight ACROSS the barrier (never vmcnt(0) in a main loop).
#define PHASE(WAITN) do { \
        asm volatile("s_waitcnt vmcnt(" #WAITN ")" ::: "memory"); \
        __builtin_amdgcn_s_barrier(); \
        asm volatile("" ::: "memory"); \
        __builtin_amdgcn_sched_barrier(0); } while (0)

// ---------------------------------------------------------------------------
// prep: fused f32->bf16 convert of q,k,v (blocks 0..6143) + weight transpose
// (blocks 6144..7167). Ts row stride 68 u16 (was 72): with 72 the transpose
// read bank index was independent of c -> 8-way scalar-read conflict; 68
// gives (16c+2j+r/2)%32 -> 2-way.
// ---------------------------------------------------------------------------
__global__ __launch_bounds__(256) void prep(
    const float* __restrict__ q, const float* __restrict__ k, const float* __restrict__ v,
    unsigned short* __restrict__ qb, unsigned short* __restrict__ kb, unsigned short* __restrict__ vb,
    const float* __restrict__ W0, const float* __restrict__ W1,
    const float* __restrict__ W2, const float* __restrict__ W3,
    unsigned short* __restrict__ T0, unsigned short* __restrict__ T1,
    unsigned short* __restrict__ T2, unsigned short* __restrict__ T3)
{
    __shared__ unsigned short Ts[64 * 68];
    int bx = blockIdx.x;
    if (bx < 6144) {
        const float* src; unsigned short* dst;
        switch (bx >> 11) { case 0: src = q; dst = qb; break;
                            case 1: src = k; dst = kb; break;
                            default: src = v; dst = vb; break; }
        size_t i = ((size_t)(bx & 2047) * 256 + threadIdx.x) * 8;
        float4 x0 = *(const float4*)&src[i];
        float4 x1 = *(const float4*)&src[i + 4];
        union { unsigned short s[8]; uint4 u; } p;
        p.s[0] = f2bf(x0.x); p.s[1] = f2bf(x0.y); p.s[2] = f2bf(x0.z); p.s[3] = f2bf(x0.w);
        p.s[4] = f2bf(x1.x); p.s[5] = f2bf(x1.y); p.s[6] = f2bf(x1.z); p.s[7] = f2bf(x1.w);
        *(uint4*)&dst[i] = p.u;
        return;
    }
    int w = bx - 6144;                // 1024 blocks: z(4) x kx(16) x ny(16)
    int z = w >> 8, rem = w & 255;
    int kx = rem >> 4, ny = rem & 15;
    const float* W;
    unsigned short* T;
    switch (z) {
        case 0: W = W0; T = T0; break;
        case 1: W = W1; T = T1; break;
        case 2: W = W2; T = T2; break;
        default: W = W3; T = T3; break;
    }
    int tid = threadIdx.x;
    int c = tid & 7, r = tid >> 3;
    int k0 = kx * 64, n0 = ny * 64;
    for (int i = 0; i < 64; i += 32) {
        const float* src = &W[(size_t)(k0 + r + i) * 1024 + n0 + c * 8];
        float4 x0 = *(const float4*)src;
        float4 x1 = *(const float4*)(src + 4);
        unsigned short* d = &Ts[(r + i) * 68 + c * 8];
        d[0] = f2bf(x0.x); d[1] = f2bf(x0.y); d[2] = f2bf(x0.z); d[3] = f2bf(x0.w);
        d[4] = f2bf(x1.x); d[5] = f2bf(x1.y); d[6] = f2bf(x1.z); d[7] = f2bf(x1.w);
    }
    __syncthreads();
    for (int i = 0; i < 64; i += 32) {
        union { unsigned short s[8]; uint4 v; } u;
        for (int j = 0; j < 8; j++) u.s[j] = Ts[(c * 8 + j) * 68 + (r + i)];
        *(uint4*)&T[(size_t)(n0 + r + i) * 1024 + k0 + c * 8] = u.v;
    }
}

// ---------------------------------------------------------------------------
// GEMM core v5 (qkv): 128x128 / BK=32 / 64-B-row XOR swizzle with 3-buffer
// depth-2 counted-vmcnt pipeline (unchanged from r5).
// ---------------------------------------------------------------------------
__device__ __forceinline__ void gemm_core_p(
    const unsigned short* __restrict__ A, const unsigned short* __restrict__ BT,
    const float* __restrict__ bias, unsigned short* __restrict__ out16,
    int mode, float scale)
{
    const int K = 1024;
    __shared__ unsigned short As[3][128 * 32];
    __shared__ unsigned short Bs[3][128 * 32];
    int tid = threadIdx.x;
    int m0 = blockIdx.x * 128, n0 = blockIdx.y * 128;
    int lane = tid & 63, wave = tid >> 6;
    int lm = lane & 15, quad = lane >> 4;
    int wm = (wave >> 1) * 64, wn = (wave & 1) * 64;

    int lrow = lane >> 2;
    int scol = ((lane & 3) ^ ((lane >> 3) & 3)) * 8;
    const unsigned short* Ag = A + (size_t)(m0 + wave * 32 + lrow) * K + scol;
    const unsigned short* Bg = BT + (size_t)(n0 + wave * 32 + lrow) * K + scol;

    int rpos = (quad ^ ((lm >> 1) & 3)) * 8;

    f32x4 acc[4][4];
    for (int i = 0; i < 4; i++)
        for (int j = 0; j < 4; j++)
            for (int r = 0; r < 4; r++) acc[i][j][r] = 0.0f;

#define GSTAGE(BUF) do { \
        GLD16(Ag,          &As[BUF][(wave * 32) * 32]); \
        GLD16(Ag + 16 * K, &As[BUF][(wave * 32 + 16) * 32]); \
        GLD16(Bg,          &Bs[BUF][(wave * 32) * 32]); \
        GLD16(Bg + 16 * K, &Bs[BUF][(wave * 32 + 16) * 32]); \
        Ag += 32; Bg += 32; } while (0)

#define GCOMP(BUF) do { \
        short8 a[4], b[4]; \
        _Pragma("unroll") \
        for (int i = 0; i < 4; i++) \
            a[i] = *(const short8*)&As[BUF][(wm + i * 16 + lm) * 32 + rpos]; \
        _Pragma("unroll") \
        for (int j = 0; j < 4; j++) \
            b[j] = *(const short8*)&Bs[BUF][(wn + j * 16 + lm) * 32 + rpos]; \
        _Pragma("unroll") \
        for (int i = 0; i < 4; i++) \
            _Pragma("unroll") \
            for (int j = 0; j < 4; j++) \
                acc[i][j] = __builtin_amdgcn_mfma_f32_16x16x32_bf16(a[i], b[j], acc[i][j], 0, 0, 0); \
        } while (0)

    GSTAGE(0); GSTAGE(1);
    for (int u = 0; u < 10; u++) {
        PHASE(4); GSTAGE(2); GCOMP(0);
        PHASE(4); GSTAGE(0); GCOMP(1);
        PHASE(4); GSTAGE(1); GCOMP(2);
    }
    PHASE(4); GCOMP(0);
    PHASE(0); GCOMP(1);

#undef GSTAGE
#undef GCOMP

    for (int j = 0; j < 4; j++) {
        int col = n0 + wn + j * 16 + lm;
        float bv = bias[col];
        for (int i = 0; i < 4; i++) {
            int rowb = m0 + wm + i * 16 + quad * 4;
            int h = col >> 6, d = col & 63;
            int bb = rowb >> 11, t = rowb & 2047;
            if (mode == 1) {
                size_t base = (((size_t)(bb * 16 + h)) * 2048 + t) * 64 + d;
                for (int r = 0; r < 4; r++)
                    out16[base + (size_t)r * 64] = f2bf((acc[i][j][r] + bv) * scale);
            } else {
                ushort4 pk;                       // t is 4-aligned
                pk.x = f2bf((acc[i][j][0] + bv) * scale);
                pk.y = f2bf((acc[i][j][1] + bv) * scale);
                pk.z = f2bf((acc[i][j][2] + bv) * scale);
                pk.w = f2bf((acc[i][j][3] + bv) * scale);
                *(ushort4*)&out16[(((size_t)(bb * 16 + h)) * 64 + d) * 2048 + t] = pk;
            }
        }
    }
}

__global__ __launch_bounds__(256, 3) void qkv_gemm(
    const unsigned short* __restrict__ qbf, const unsigned short* __restrict__ kbf,
    const unsigned short* __restrict__ vbf,
    const unsigned short* __restrict__ WqT, const unsigned short* __restrict__ WkT,
    const unsigned short* __restrict__ WvT,
    const float* __restrict__ bq, const float* __restrict__ bk, const float* __restrict__ bv,
    unsigned short* __restrict__ Qh, unsigned short* __restrict__ Kh,
    unsigned short* __restrict__ VhT)
{
    switch (blockIdx.z) {
        case 0:  gemm_core_p(qbf, WqT, bq, Qh,  1, 0.18033688011f); break; // log2e/8
        case 1:  gemm_core_p(kbf, WkT, bk, Kh,  1, 1.0f);           break;
        default: gemm_core_p(vbf, WvT, bv, VhT, 2, 1.0f);           break;
    }
}

// ---------------------------------------------------------------------------
// out GEMM v5: 128x64 tile (grid 512 = 2 blocks/CU), BK=32, 3-buffer
// counted-vmcnt pipeline (unchanged from r5).
// ---------------------------------------------------------------------------
__global__ __launch_bounds__(256, 2) void out_gemm(
    const unsigned short* __restrict__ A, const unsigned short* __restrict__ BT,
    const float* __restrict__ bias, float* __restrict__ out)
{
    const int K = 1024;
    __shared__ unsigned short As[3][128 * 32];
    __shared__ unsigned short Bs[3][64 * 32];
    int tid = threadIdx.x;
    int m0 = blockIdx.x * 128, n0 = blockIdx.y * 64;
    int lane = tid & 63, wave = tid >> 6;
    int lm = lane & 15, quad = lane >> 4;
    int wm = wave * 32;

    int lrow = lane >> 2;
    int scol = ((lane & 3) ^ ((lane >> 3) & 3)) * 8;
    const unsigned short* Ag = A + (size_t)(m0 + wave * 32 + lrow) * K + scol;
    const unsigned short* Bg = BT + (size_t)(n0 + wave * 16 + lrow) * K + scol;

    int rpos = (quad ^ ((lm >> 1) & 3)) * 8;

    f32x4 acc[2][4];
    for (int i = 0; i < 2; i++)
        for (int j = 0; j < 4; j++)
            for (int r = 0; r < 4; r++) acc[i][j][r] = 0.0f;

#define OSTAGE(BUF) do { \
        GLD16(Ag,          &As[BUF][(wave * 32) * 32]); \
        GLD16(Ag + 16 * K, &As[BUF][(wave * 32 + 16) * 32]); \
        GLD16(Bg,          &Bs[BUF][(wave * 16) * 32]); \
        Ag += 32; Bg += 32; } while (0)

#define OCOMP(BUF) do { \
        short8 a[2], b[4]; \
        _Pragma("unroll") \
        for (int i = 0; i < 2; i++) \
            a[i] = *(const short8*)&As[BUF][(wm + i * 16 + lm) * 32 + rpos]; \
        _Pragma("unroll") \
        for (int j = 0; j < 4; j++) \
            b[j] = *(const short8*)&Bs[BUF][(j * 16 + lm) * 32 + rpos]; \
        _Pragma("unroll") \
        for (int i = 0; i < 2; i++) \
            _Pragma("unroll") \
            for (int j = 0; j < 4; j++) \
                acc[i][j] = __builtin_amdgcn_mfma_f32_16x16x32_bf16(a[i], b[j], acc[i][j], 0, 0, 0); \
        } while (0)

    OSTAGE(0); OSTAGE(1);
    for (int u = 0; u < 10; u++) {
        PHASE(3); OSTAGE(2); OCOMP(0);
        PHASE(3); OSTAGE(0); OCOMP(1);
        PHASE(3); OSTAGE(1); OCOMP(2);
    }
    PHASE(3); OCOMP(0);
    PHASE(0); OCOMP(1);

#undef OSTAGE
#undef OCOMP

    for (int j = 0; j < 4; j++) {
        int col = n0 + j * 16 + lm;
        float bv = bias[col];
        for (int i = 0; i < 2; i++) {
            int rowb = m0 + wm + i * 16 + quad * 4;
            for (int r = 0; r < 4; r++)
                out[(size_t)(rowb + r) * 1024 + col] = acc[i][j][r] + bv;
        }
    }
}

// ---------------------------------------------------------------------------
// Flash attention v9: v8 + (a) XCD-aware block swizzle: w=(id&7)*64+(id>>3)
// gives each XCD 4 COMPLETE heads (2 MB K/V, L2-resident) instead of 2 qblks
// of every head (16 MB working set, thrash -> 22 MB HBM re-fetch seen in
// FETCH_SIZE 69.7 vs 48 unique); (b) T5 s_setprio(1) around the QK^T and PV
// MFMA clusters (m191 regime: staggered independent blocks) to break the
// barrier-lockstep that serializes LDS/MFMA/VALU pipes (sum of pipe times
// ~= measured 54.4us => near-zero cross-wave overlap today).
// ---------------------------------------------------------------------------
__global__ __launch_bounds__(256) void attn_kernel(
    const unsigned short* __restrict__ Qh, const unsigned short* __restrict__ Kh,
    const unsigned short* __restrict__ VhT, unsigned short* __restrict__ X)
{
    __shared__ unsigned short Ks[4][64 * 64];
    __shared__ unsigned short Vt[4][64 * 64];

    int tid = threadIdx.x;
    // XCD swizzle: physical XCD = blockIdx.x % 8; give XCD g logical work
    // w in [64g, 64g+64) = heads 4g..4g+3, all 16 qblks each.
    int wid = (blockIdx.x & 7) * 64 + (blockIdx.x >> 3);
    int qblk = wid & 15, bh = wid >> 4;
    int b = bh >> 4, h = bh & 15;
    int lane = tid & 63, wave = tid >> 6;
    int lm = lane & 15, quad = lane >> 4;

    const unsigned short* Kbase = Kh + (size_t)bh * 2048 * 64;
    const unsigned short* Vbase = VhT + (size_t)bh * 64 * 2048;

    int srow = wave * 8 + (lane >> 3);
    int schk = ((lane & 7) ^ ((lane >> 3) & 7)) * 8;
    int swz  = lm & 7;

    // loop-invariant per-lane LDS byte bases; buffer i lives at +i*8192 bytes
    const char* ks0 = (const char*)&Ks[0][0] + lm * 128 + ((quad ^ swz) * 16);
    const char* ks1 = (const char*)&Ks[0][0] + lm * 128 + (((quad + 4) ^ swz) * 16);
    int qh2 = quad >> 1, wo = (quad & 1) * 8;            // bytes
    const char* vt0 = (const char*)&Vt[0][0] + lm * 128 + (((0 + qh2) ^ swz) * 16) + wo;
    const char* vt1 = (const char*)&Vt[0][0] + lm * 128 + (((2 + qh2) ^ swz) * 16) + wo;
    const char* vt2 = (const char*)&Vt[0][0] + lm * 128 + (((4 + qh2) ^ swz) * 16) + wo;
    const char* vt3 = (const char*)&Vt[0][0] + lm * 128 + (((6 + qh2) ^ swz) * 16) + wo;

    // incremented global staging pointers (tile stride: K += 64 rows, V += 64 cols)
    const unsigned short* Kg = Kbase + (size_t)srow * 64 + schk;
    const unsigned short* Vg = Vbase + (size_t)srow * 2048 + schk;

    // two q-row groups per wave: rows qblk*128 + wave*32 + lm (+16)
    int qrow = qblk * 128 + wave * 32 + lm;
    const unsigned short* qptr = Qh + ((size_t)bh * 2048 + qrow) * 64;
    short8 qfa0 = *(const short8*)&qptr[quad * 8];
    short8 qfa1 = *(const short8*)&qptr[32 + quad * 8];
    short8 qfb0 = *(const short8*)&qptr[16 * 64 + quad * 8];
    short8 qfb1 = *(const short8*)&qptr[16 * 64 + 32 + quad * 8];
    // drain Q loads so in-loop vmcnt counts ONLY the 4-per-tile staging loads
    asm volatile("s_waitcnt vmcnt(0)" ::: "memory");

    f32x4 oA[4], oB[4];
    for (int n = 0; n < 4; n++)
        for (int r = 0; r < 4; r++) { oA[n][r] = 0.0f; oB[n][r] = 0.0f; }
    float lA = 0.0f, lB = 0.0f;
    f32x4 zf;
    zf[0] = zf[1] = zf[2] = zf[3] = 0.0f;

#define STAGE(BUF) do { \
        GLD16(Kg,             &Ks[BUF][(wave * 8) * 64]); \
        GLD16(Kg + 32 * 64,   &Ks[BUF][(32 + wave * 8) * 64]); \
        GLD16(Vg,             &Vt[BUF][(wave * 8) * 64]); \
        GLD16(Vg + 32 * 2048, &Vt[BUF][(32 + wave * 8) * 64]); \
        Kg += 64 * 64; Vg += 64; } while (0)

#define QKPV(CUR) do { \
        short4v pa[4], pb[4]; \
        _Pragma("unroll") \
        for (int t = 0; t < 4; t++) { \
            short8 ka0 = *(const short8*)(ks0 + (CUR) * 8192 + t * 2048); \
            short8 ka1 = *(const short8*)(ks1 + (CUR) * 8192 + t * 2048); \
            __builtin_amdgcn_s_setprio(1); \
            f32x4 za = __builtin_amdgcn_mfma_f32_16x16x32_bf16(ka0, qfa0, zf, 0, 0, 0); \
            za = __builtin_amdgcn_mfma_f32_16x16x32_bf16(ka1, qfa1, za, 0, 0, 0); \
            f32x4 zb = __builtin_amdgcn_mfma_f32_16x16x32_bf16(ka0, qfb0, zf, 0, 0, 0); \
            zb = __builtin_amdgcn_mfma_f32_16x16x32_bf16(ka1, qfb1, zb, 0, 0, 0); \
            __builtin_amdgcn_s_setprio(0); \
            float a0 = __builtin_amdgcn_exp2f(za[0]); \
            float a1 = __builtin_amdgcn_exp2f(za[1]); \
            float a2 = __builtin_amdgcn_exp2f(za[2]); \
            float a3 = __builtin_amdgcn_exp2f(za[3]); \
            lA += (a0 + a1) + (a2 + a3); \
            pa[t] = pack4bf(a0, a1, a2, a3); \
            float b0 = __builtin_amdgcn_exp2f(zb[0]); \
            float b1 = __builtin_amdgcn_exp2f(zb[1]); \
            float b2 = __builtin_amdgcn_exp2f(zb[2]); \
            float b3 = __builtin_amdgcn_exp2f(zb[3]); \
            lB += (b0 + b1) + (b2 + b3); \
            pb[t] = pack4bf(b0, b1, b2, b3); \
        } \
        __builtin_amdgcn_s_setprio(1); \
        _Pragma("unroll") \
        for (int n = 0; n < 4; n++) { \
            short4v v0 = *(const short4v*)(vt0 + (CUR) * 8192 + n * 2048); \
            short4v v1 = *(const short4v*)(vt1 + (CUR) * 8192 + n * 2048); \
            short4v v2 = *(const short4v*)(vt2 + (CUR) * 8192 + n * 2048); \
            short4v v3 = *(const short4v*)(vt3 + (CUR) * 8192 + n * 2048); \
            oA[n] = __builtin_amdgcn_mfma_f32_16x16x16bf16_1k(pa[0], v0, oA[n], 0, 0, 0); \
            oB[n] = __builtin_amdgcn_mfma_f32_16x16x16bf16_1k(pb[0], v0, oB[n], 0, 0, 0); \
            oA[n] = __builtin_amdgcn_mfma_f32_16x16x16bf16_1k(pa[1], v1, oA[n], 0, 0, 0); \
            oB[n] = __builtin_amdgcn_mfma_f32_16x16x16bf16_1k(pb[1], v1, oB[n], 0, 0, 0); \
            oA[n] = __builtin_amdgcn_mfma_f32_16x16x16bf16_1k(pa[2], v2, oA[n], 0, 0, 0); \
            oB[n] = __builtin_amdgcn_mfma_f32_16x16x16bf16_1k(pb[2], v2, oB[n], 0, 0, 0); \
            oA[n] = __builtin_amdgcn_mfma_f32_16x16x16bf16_1k(pa[3], v3, oA[n], 0, 0, 0); \
            oB[n] = __builtin_amdgcn_mfma_f32_16x16x16bf16_1k(pb[3], v3, oB[n], 0, 0, 0); \
        } \
        __builtin_amdgcn_s_setprio(0); \
        } while (0)

    // prologue: tiles 0,1,2 in flight (12 loads)
    STAGE(0); STAGE(1); STAGE(2);

    // t = 0..27: wait tile t (vmcnt 12->8), stage tile t+3, compute tile t
    for (int u = 0; u < 7; u++) {
        PHASE(8); STAGE(3); QKPV(0);
        PHASE(8); STAGE(0); QKPV(1);
        PHASE(8); STAGE(1); QKPV(2);
        PHASE(8); STAGE(2); QKPV(3);
    }
    // t = 28: stage tile 31; t = 29..31: drain
    PHASE(8); STAGE(3); QKPV(0);
    PHASE(8); QKPV(1);
    PHASE(4); QKPV(2);
    PHASE(0); QKPV(3);

#undef STAGE
#undef QKPV

    lA += __shfl_xor(lA, 16);
    lA += __shfl_xor(lA, 32);
    lB += __shfl_xor(lB, 16);
    lB += __shfl_xor(lB, 32);
    float invA = 1.0f / lA;
    float invB = 1.0f / lB;

    for (int r = 0; r < 4; r++) {
        int src = (lane & 48) | (quad * 4 + r);
        float invAr = __shfl(invA, src);
        float invBr = __shfl(invB, src);
        int rowA = qblk * 128 + wave * 32 + quad * 4 + r;
        for (int n = 0; n < 4; n++) {
            X[((size_t)b * 2048 + rowA) * 1024 + h * 64 + n * 16 + lm] = f2bf(oA[n][r] * invAr);
            X[((size_t)b * 2048 + rowA + 16) * 1024 + h * 64 + n * 16 + lm] = f2bf(oB[n][r] * invBr);
        }
    }
}

// ---------------------------------------------------------------------------
extern "C" void kernel_launch(void* const* d_in, const int* in_sizes, int n_in,
                              void* d_out, int out_size, void* d_ws, size_t ws_size,
                              hipStream_t stream)
{
    const float* q  = (const float*)d_in[0];
    const float* k  = (const float*)d_in[1];
    const float* v  = (const float*)d_in[2];
    const float* Wq = (const float*)d_in[3];
    const float* bq = (const float*)d_in[4];
    const float* Wk = (const float*)d_in[5];
    const float* bk = (const float*)d_in[6];
    const float* Wv = (const float*)d_in[7];
    const float* bv = (const float*)d_in[8];
    const float* Wo = (const float*)d_in[9];
    const float* bo = (const float*)d_in[10];

    // 40 MB ws layout, sequential aliasing:
    //  0- 4M: WqT,WkT,WvT,WoT (1M elems each)
    //  4- 8M: qbf -> Kh | 8-12M: kbf -> VhT | 12-16M: vbf -> X | 16-20M: Qh
    unsigned short* ws  = (unsigned short*)d_ws;
    const unsigned int M1 = 1u << 20;
    unsigned short* WqT = ws;
    unsigned short* WkT = ws + M1;
    unsigned short* WvT = ws + 2 * M1;
    unsigned short* WoT = ws + 3 * M1;
    unsigned short* qbf = ws + 4 * M1;
    unsigned short* kbf = ws + 8 * M1;
    unsigned short* vbf = ws + 12 * M1;
    unsigned short* Qh  = ws + 16 * M1;
    unsigned short* Kh  = ws + 4 * M1;    // over dead qbf
    unsigned short* VhT = ws + 8 * M1;    // over dead kbf
    unsigned short* X   = ws + 12 * M1;   // over dead vbf

    prep<<<dim3(7168), 256, 0, stream>>>(q, k, v, qbf, kbf, vbf,
                                         Wq, Wk, Wv, Wo, WqT, WkT, WvT, WoT);
    qkv_gemm<<<dim3(32, 8, 3), 256, 0, stream>>>(qbf, kbf, vbf, WqT, WkT, WvT,
                                                 bq, bk, bv, Qh, Kh, VhT);
    attn_kernel<<<dim3(512), 256, 0, stream>>>(Qh, Kh, VhT, X);
    out_gemm<<<dim3(32, 16), 256, 0, stream>>>(X, WoT, bo, (float*)d_out);
}

// Round 7
// 218.432 us; speedup vs baseline: 1.0141x; 1.0141x over previous
//
#include <hip/hip_runtime.h>
#include <hip/hip_bf16.h>

typedef __attribute__((ext_vector_type(8))) short short8;
typedef __attribute__((ext_vector_type(4))) short short4v;
typedef __attribute__((ext_vector_type(4))) float f32x4;

__device__ __forceinline__ unsigned short f2bf(float f) {
    __hip_bfloat16 h = __float2bfloat16(f);
    unsigned short u;
    __builtin_memcpy(&u, &h, 2);
    return u;
}
// packed RNE f32->bf16 pairs: compiles to v_cvt_pk_bf16_f32
__device__ __forceinline__ short4v pack4bf(float a, float b, float c, float d) {
    union { __hip_bfloat162 h[2]; short4v s; } r;
    r.h[0] = __float22bfloat162_rn(make_float2(a, b));
    r.h[1] = __float22bfloat162_rn(make_float2(c, d));
    return r.s;
}
// concat two 4-element bf16 fragments into a K=32 MFMA operand
union cat8 { short4v h[2]; short8 v8; };

#define GLD16(gp, lp) __builtin_amdgcn_global_load_lds( \
    (const __attribute__((address_space(1))) void*)(gp), \
    (__attribute__((address_space(3))) void*)(lp), 16, 0, 0)

// counted-vmcnt barrier: retire current tile's loads, keep next tiles' in
// flight ACROSS the barrier (never vmcnt(0) in a main loop).
#define PHASE(WAITN) do { \
        asm volatile("s_waitcnt vmcnt(" #WAITN ")" ::: "memory"); \
        __builtin_amdgcn_s_barrier(); \
        asm volatile("" ::: "memory"); \
        __builtin_amdgcn_sched_barrier(0); } while (0)

// ---------------------------------------------------------------------------
// prep: fused f32->bf16 convert of q,k,v (blocks 0..6143) + weight transpose
// (blocks 6144..7167). Ts row stride 68 u16 (2-way transpose-read banks).
// ---------------------------------------------------------------------------
__global__ __launch_bounds__(256) void prep(
    const float* __restrict__ q, const float* __restrict__ k, const float* __restrict__ v,
    unsigned short* __restrict__ qb, unsigned short* __restrict__ kb, unsigned short* __restrict__ vb,
    const float* __restrict__ W0, const float* __restrict__ W1,
    const float* __restrict__ W2, const float* __restrict__ W3,
    unsigned short* __restrict__ T0, unsigned short* __restrict__ T1,
    unsigned short* __restrict__ T2, unsigned short* __restrict__ T3)
{
    __shared__ unsigned short Ts[64 * 68];
    int bx = blockIdx.x;
    if (bx < 6144) {
        const float* src; unsigned short* dst;
        switch (bx >> 11) { case 0: src = q; dst = qb; break;
                            case 1: src = k; dst = kb; break;
                            default: src = v; dst = vb; break; }
        size_t i = ((size_t)(bx & 2047) * 256 + threadIdx.x) * 8;
        float4 x0 = *(const float4*)&src[i];
        float4 x1 = *(const float4*)&src[i + 4];
        union { unsigned short s[8]; uint4 u; } p;
        p.s[0] = f2bf(x0.x); p.s[1] = f2bf(x0.y); p.s[2] = f2bf(x0.z); p.s[3] = f2bf(x0.w);
        p.s[4] = f2bf(x1.x); p.s[5] = f2bf(x1.y); p.s[6] = f2bf(x1.z); p.s[7] = f2bf(x1.w);
        *(uint4*)&dst[i] = p.u;
        return;
    }
    int w = bx - 6144;                // 1024 blocks: z(4) x kx(16) x ny(16)
    int z = w >> 8, rem = w & 255;
    int kx = rem >> 4, ny = rem & 15;
    const float* W;
    unsigned short* T;
    switch (z) {
        case 0: W = W0; T = T0; break;
        case 1: W = W1; T = T1; break;
        case 2: W = W2; T = T2; break;
        default: W = W3; T = T3; break;
    }
    int tid = threadIdx.x;
    int c = tid & 7, r = tid >> 3;
    int k0 = kx * 64, n0 = ny * 64;
    for (int i = 0; i < 64; i += 32) {
        const float* src = &W[(size_t)(k0 + r + i) * 1024 + n0 + c * 8];
        float4 x0 = *(const float4*)src;
        float4 x1 = *(const float4*)(src + 4);
        unsigned short* d = &Ts[(r + i) * 68 + c * 8];
        d[0] = f2bf(x0.x); d[1] = f2bf(x0.y); d[2] = f2bf(x0.z); d[3] = f2bf(x0.w);
        d[4] = f2bf(x1.x); d[5] = f2bf(x1.y); d[6] = f2bf(x1.z); d[7] = f2bf(x1.w);
    }
    __syncthreads();
    for (int i = 0; i < 64; i += 32) {
        union { unsigned short s[8]; uint4 v; } u;
        for (int j = 0; j < 8; j++) u.s[j] = Ts[(c * 8 + j) * 68 + (r + i)];
        *(uint4*)&T[(size_t)(n0 + r + i) * 1024 + k0 + c * 8] = u.v;
    }
}

// ---------------------------------------------------------------------------
// GEMM core v5 (qkv): 128x128 / BK=32 / 64-B-row XOR swizzle with 3-buffer
// depth-2 counted-vmcnt pipeline (unchanged from r5).
// ---------------------------------------------------------------------------
__device__ __forceinline__ void gemm_core_p(
    const unsigned short* __restrict__ A, const unsigned short* __restrict__ BT,
    const float* __restrict__ bias, unsigned short* __restrict__ out16,
    int mode, float scale)
{
    const int K = 1024;
    __shared__ unsigned short As[3][128 * 32];
    __shared__ unsigned short Bs[3][128 * 32];
    int tid = threadIdx.x;
    int m0 = blockIdx.x * 128, n0 = blockIdx.y * 128;
    int lane = tid & 63, wave = tid >> 6;
    int lm = lane & 15, quad = lane >> 4;
    int wm = (wave >> 1) * 64, wn = (wave & 1) * 64;

    int lrow = lane >> 2;
    int scol = ((lane & 3) ^ ((lane >> 3) & 3)) * 8;
    const unsigned short* Ag = A + (size_t)(m0 + wave * 32 + lrow) * K + scol;
    const unsigned short* Bg = BT + (size_t)(n0 + wave * 32 + lrow) * K + scol;

    int rpos = (quad ^ ((lm >> 1) & 3)) * 8;

    f32x4 acc[4][4];
    for (int i = 0; i < 4; i++)
        for (int j = 0; j < 4; j++)
            for (int r = 0; r < 4; r++) acc[i][j][r] = 0.0f;

#define GSTAGE(BUF) do { \
        GLD16(Ag,          &As[BUF][(wave * 32) * 32]); \
        GLD16(Ag + 16 * K, &As[BUF][(wave * 32 + 16) * 32]); \
        GLD16(Bg,          &Bs[BUF][(wave * 32) * 32]); \
        GLD16(Bg + 16 * K, &Bs[BUF][(wave * 32 + 16) * 32]); \
        Ag += 32; Bg += 32; } while (0)

#define GCOMP(BUF) do { \
        short8 a[4], b[4]; \
        _Pragma("unroll") \
        for (int i = 0; i < 4; i++) \
            a[i] = *(const short8*)&As[BUF][(wm + i * 16 + lm) * 32 + rpos]; \
        _Pragma("unroll") \
        for (int j = 0; j < 4; j++) \
            b[j] = *(const short8*)&Bs[BUF][(wn + j * 16 + lm) * 32 + rpos]; \
        _Pragma("unroll") \
        for (int i = 0; i < 4; i++) \
            _Pragma("unroll") \
            for (int j = 0; j < 4; j++) \
                acc[i][j] = __builtin_amdgcn_mfma_f32_16x16x32_bf16(a[i], b[j], acc[i][j], 0, 0, 0); \
        } while (0)

    GSTAGE(0); GSTAGE(1);
    for (int u = 0; u < 10; u++) {
        PHASE(4); GSTAGE(2); GCOMP(0);
        PHASE(4); GSTAGE(0); GCOMP(1);
        PHASE(4); GSTAGE(1); GCOMP(2);
    }
    PHASE(4); GCOMP(0);
    PHASE(0); GCOMP(1);

#undef GSTAGE
#undef GCOMP

    for (int j = 0; j < 4; j++) {
        int col = n0 + wn + j * 16 + lm;
        float bv = bias[col];
        for (int i = 0; i < 4; i++) {
            int rowb = m0 + wm + i * 16 + quad * 4;
            int h = col >> 6, d = col & 63;
            int bb = rowb >> 11, t = rowb & 2047;
            if (mode == 1) {
                size_t base = (((size_t)(bb * 16 + h)) * 2048 + t) * 64 + d;
                for (int r = 0; r < 4; r++)
                    out16[base + (size_t)r * 64] = f2bf((acc[i][j][r] + bv) * scale);
            } else {
                ushort4 pk;                       // t is 4-aligned
                pk.x = f2bf((acc[i][j][0] + bv) * scale);
                pk.y = f2bf((acc[i][j][1] + bv) * scale);
                pk.z = f2bf((acc[i][j][2] + bv) * scale);
                pk.w = f2bf((acc[i][j][3] + bv) * scale);
                *(ushort4*)&out16[(((size_t)(bb * 16 + h)) * 64 + d) * 2048 + t] = pk;
            }
        }
    }
}

__global__ __launch_bounds__(256, 3) void qkv_gemm(
    const unsigned short* __restrict__ qbf, const unsigned short* __restrict__ kbf,
    const unsigned short* __restrict__ vbf,
    const unsigned short* __restrict__ WqT, const unsigned short* __restrict__ WkT,
    const unsigned short* __restrict__ WvT,
    const float* __restrict__ bq, const float* __restrict__ bk, const float* __restrict__ bv,
    unsigned short* __restrict__ Qh, unsigned short* __restrict__ Kh,
    unsigned short* __restrict__ VhT)
{
    switch (blockIdx.z) {
        case 0:  gemm_core_p(qbf, WqT, bq, Qh,  1, 0.18033688011f); break; // log2e/8
        case 1:  gemm_core_p(kbf, WkT, bk, Kh,  1, 1.0f);           break;
        default: gemm_core_p(vbf, WvT, bv, VhT, 2, 1.0f);           break;
    }
}

// ---------------------------------------------------------------------------
// out GEMM v5: 128x64 tile (grid 512 = 2 blocks/CU), BK=32, 3-buffer
// counted-vmcnt pipeline (unchanged from r5).
// ---------------------------------------------------------------------------
__global__ __launch_bounds__(256, 2) void out_gemm(
    const unsigned short* __restrict__ A, const unsigned short* __restrict__ BT,
    const float* __restrict__ bias, float* __restrict__ out)
{
    const int K = 1024;
    __shared__ unsigned short As[3][128 * 32];
    __shared__ unsigned short Bs[3][64 * 32];
    int tid = threadIdx.x;
    int m0 = blockIdx.x * 128, n0 = blockIdx.y * 64;
    int lane = tid & 63, wave = tid >> 6;
    int lm = lane & 15, quad = lane >> 4;
    int wm = wave * 32;

    int lrow = lane >> 2;
    int scol = ((lane & 3) ^ ((lane >> 3) & 3)) * 8;
    const unsigned short* Ag = A + (size_t)(m0 + wave * 32 + lrow) * K + scol;
    const unsigned short* Bg = BT + (size_t)(n0 + wave * 16 + lrow) * K + scol;

    int rpos = (quad ^ ((lm >> 1) & 3)) * 8;

    f32x4 acc[2][4];
    for (int i = 0; i < 2; i++)
        for (int j = 0; j < 4; j++)
            for (int r = 0; r < 4; r++) acc[i][j][r] = 0.0f;

#define OSTAGE(BUF) do { \
        GLD16(Ag,          &As[BUF][(wave * 32) * 32]); \
        GLD16(Ag + 16 * K, &As[BUF][(wave * 32 + 16) * 32]); \
        GLD16(Bg,          &Bs[BUF][(wave * 16) * 32]); \
        Ag += 32; Bg += 32; } while (0)

#define OCOMP(BUF) do { \
        short8 a[2], b[4]; \
        _Pragma("unroll") \
        for (int i = 0; i < 2; i++) \
            a[i] = *(const short8*)&As[BUF][(wm + i * 16 + lm) * 32 + rpos]; \
        _Pragma("unroll") \
        for (int j = 0; j < 4; j++) \
            b[j] = *(const short8*)&Bs[BUF][(j * 16 + lm) * 32 + rpos]; \
        _Pragma("unroll") \
        for (int i = 0; i < 2; i++) \
            _Pragma("unroll") \
            for (int j = 0; j < 4; j++) \
                acc[i][j] = __builtin_amdgcn_mfma_f32_16x16x32_bf16(a[i], b[j], acc[i][j], 0, 0, 0); \
        } while (0)

    OSTAGE(0); OSTAGE(1);
    for (int u = 0; u < 10; u++) {
        PHASE(3); OSTAGE(2); OCOMP(0);
        PHASE(3); OSTAGE(0); OCOMP(1);
        PHASE(3); OSTAGE(1); OCOMP(2);
    }
    PHASE(3); OCOMP(0);
    PHASE(0); OCOMP(1);

#undef OSTAGE
#undef OCOMP

    for (int j = 0; j < 4; j++) {
        int col = n0 + j * 16 + lm;
        float bv = bias[col];
        for (int i = 0; i < 2; i++) {
            int rowb = m0 + wm + i * 16 + quad * 4;
            for (int r = 0; r < 4; r++)
                out[(size_t)(rowb + r) * 1024 + col] = acc[i][j][r] + bv;
        }
    }
}

// ---------------------------------------------------------------------------
// Flash attention v10: R5 base (no XCD swizzle, no setprio — both A/B'd null
// or negative in r6) + PV at FULL matrix-pipe rate. r6 closed the model:
// MFMA busy 20.2us == 16x 16x16x32 (QK^T) + 32x 16x16x16_1k (PV) at a
// ~4.85cy issue slot each => the K=16 legacy op runs the pipe at HALF rate.
// Fix: MFMA dot products are invariant under a SHARED permutation of k-slots;
// pa[t] (keys 16t+4q+r) and vt(t) (same key mapping) agree slot-for-slot, so
// concat(pa[2u],pa[2u+1]) x concat(v(2u),v(2u+1)) is a legal 16x16x32 pair
// covering keys 32u..32u+31. PV: 16 K=32 MFMAs/tile (was 32 K=16), zero
// extra VALU, no cross-lane exchange.
// ---------------------------------------------------------------------------
__global__ __launch_bounds__(256) void attn_kernel(
    const unsigned short* __restrict__ Qh, const unsigned short* __restrict__ Kh,
    const unsigned short* __restrict__ VhT, unsigned short* __restrict__ X)
{
    __shared__ unsigned short Ks[4][64 * 64];
    __shared__ unsigned short Vt[4][64 * 64];

    int tid = threadIdx.x;
    int qblk = blockIdx.x & 15, bh = blockIdx.x >> 4;
    int b = bh >> 4, h = bh & 15;
    int lane = tid & 63, wave = tid >> 6;
    int lm = lane & 15, quad = lane >> 4;

    const unsigned short* Kbase = Kh + (size_t)bh * 2048 * 64;
    const unsigned short* Vbase = VhT + (size_t)bh * 64 * 2048;

    int srow = wave * 8 + (lane >> 3);
    int schk = ((lane & 7) ^ ((lane >> 3) & 7)) * 8;
    int swz  = lm & 7;

    // loop-invariant per-lane LDS byte bases; buffer i lives at +i*8192 bytes
    const char* ks0 = (const char*)&Ks[0][0] + lm * 128 + ((quad ^ swz) * 16);
    const char* ks1 = (const char*)&Ks[0][0] + lm * 128 + (((quad + 4) ^ swz) * 16);
    int qh2 = quad >> 1, wo = (quad & 1) * 8;            // bytes
    const char* vt0 = (const char*)&Vt[0][0] + lm * 128 + (((0 + qh2) ^ swz) * 16) + wo;
    const char* vt1 = (const char*)&Vt[0][0] + lm * 128 + (((2 + qh2) ^ swz) * 16) + wo;
    const char* vt2 = (const char*)&Vt[0][0] + lm * 128 + (((4 + qh2) ^ swz) * 16) + wo;
    const char* vt3 = (const char*)&Vt[0][0] + lm * 128 + (((6 + qh2) ^ swz) * 16) + wo;

    // incremented global staging pointers (tile stride: K += 64 rows, V += 64 cols)
    const unsigned short* Kg = Kbase + (size_t)srow * 64 + schk;
    const unsigned short* Vg = Vbase + (size_t)srow * 2048 + schk;

    // two q-row groups per wave: rows qblk*128 + wave*32 + lm (+16)
    int qrow = qblk * 128 + wave * 32 + lm;
    const unsigned short* qptr = Qh + ((size_t)bh * 2048 + qrow) * 64;
    short8 qfa0 = *(const short8*)&qptr[quad * 8];
    short8 qfa1 = *(const short8*)&qptr[32 + quad * 8];
    short8 qfb0 = *(const short8*)&qptr[16 * 64 + quad * 8];
    short8 qfb1 = *(const short8*)&qptr[16 * 64 + 32 + quad * 8];
    // drain Q loads so in-loop vmcnt counts ONLY the 4-per-tile staging loads
    asm volatile("s_waitcnt vmcnt(0)" ::: "memory");

    f32x4 oA[4], oB[4];
    for (int n = 0; n < 4; n++)
        for (int r = 0; r < 4; r++) { oA[n][r] = 0.0f; oB[n][r] = 0.0f; }
    float lA = 0.0f, lB = 0.0f;
    f32x4 zf;
    zf[0] = zf[1] = zf[2] = zf[3] = 0.0f;

#define STAGE(BUF) do { \
        GLD16(Kg,             &Ks[BUF][(wave * 8) * 64]); \
        GLD16(Kg + 32 * 64,   &Ks[BUF][(32 + wave * 8) * 64]); \
        GLD16(Vg,             &Vt[BUF][(wave * 8) * 64]); \
        GLD16(Vg + 32 * 2048, &Vt[BUF][(32 + wave * 8) * 64]); \
        Kg += 64 * 64; Vg += 64; } while (0)

#define QKPV(CUR) do { \
        short4v pa[4], pb[4]; \
        _Pragma("unroll") \
        for (int t = 0; t < 4; t++) { \
            short8 ka0 = *(const short8*)(ks0 + (CUR) * 8192 + t * 2048); \
            short8 ka1 = *(const short8*)(ks1 + (CUR) * 8192 + t * 2048); \
            f32x4 za = __builtin_amdgcn_mfma_f32_16x16x32_bf16(ka0, qfa0, zf, 0, 0, 0); \
            za = __builtin_amdgcn_mfma_f32_16x16x32_bf16(ka1, qfa1, za, 0, 0, 0); \
            f32x4 zb = __builtin_amdgcn_mfma_f32_16x16x32_bf16(ka0, qfb0, zf, 0, 0, 0); \
            zb = __builtin_amdgcn_mfma_f32_16x16x32_bf16(ka1, qfb1, zb, 0, 0, 0); \
            float a0 = __builtin_amdgcn_exp2f(za[0]); \
            float a1 = __builtin_amdgcn_exp2f(za[1]); \
            float a2 = __builtin_amdgcn_exp2f(za[2]); \
            float a3 = __builtin_amdgcn_exp2f(za[3]); \
            lA += (a0 + a1) + (a2 + a3); \
            pa[t] = pack4bf(a0, a1, a2, a3); \
            float b0 = __builtin_amdgcn_exp2f(zb[0]); \
            float b1 = __builtin_amdgcn_exp2f(zb[1]); \
            float b2 = __builtin_amdgcn_exp2f(zb[2]); \
            float b3 = __builtin_amdgcn_exp2f(zb[3]); \
            lB += (b0 + b1) + (b2 + b3); \
            pb[t] = pack4bf(b0, b1, b2, b3); \
        } \
        cat8 pA0, pA1, pB0, pB1; \
        pA0.h[0] = pa[0]; pA0.h[1] = pa[1]; \
        pA1.h[0] = pa[2]; pA1.h[1] = pa[3]; \
        pB0.h[0] = pb[0]; pB0.h[1] = pb[1]; \
        pB1.h[0] = pb[2]; pB1.h[1] = pb[3]; \
        _Pragma("unroll") \
        for (int n = 0; n < 4; n++) { \
            cat8 v01, v23; \
            v01.h[0] = *(const short4v*)(vt0 + (CUR) * 8192 + n * 2048); \
            v01.h[1] = *(const short4v*)(vt1 + (CUR) * 8192 + n * 2048); \
            v23.h[0] = *(const short4v*)(vt2 + (CUR) * 8192 + n * 2048); \
            v23.h[1] = *(const short4v*)(vt3 + (CUR) * 8192 + n * 2048); \
            oA[n] = __builtin_amdgcn_mfma_f32_16x16x32_bf16(pA0.v8, v01.v8, oA[n], 0, 0, 0); \
            oB[n] = __builtin_amdgcn_mfma_f32_16x16x32_bf16(pB0.v8, v01.v8, oB[n], 0, 0, 0); \
            oA[n] = __builtin_amdgcn_mfma_f32_16x16x32_bf16(pA1.v8, v23.v8, oA[n], 0, 0, 0); \
            oB[n] = __builtin_amdgcn_mfma_f32_16x16x32_bf16(pB1.v8, v23.v8, oB[n], 0, 0, 0); \
        } } while (0)

    // prologue: tiles 0,1,2 in flight (12 loads)
    STAGE(0); STAGE(1); STAGE(2);

    // t = 0..27: wait tile t (vmcnt 12->8), stage tile t+3, compute tile t
    for (int u = 0; u < 7; u++) {
        PHASE(8); STAGE(3); QKPV(0);
        PHASE(8); STAGE(0); QKPV(1);
        PHASE(8); STAGE(1); QKPV(2);
        PHASE(8); STAGE(2); QKPV(3);
    }
    // t = 28: stage tile 31; t = 29..31: drain
    PHASE(8); STAGE(3); QKPV(0);
    PHASE(8); QKPV(1);
    PHASE(4); QKPV(2);
    PHASE(0); QKPV(3);

#undef STAGE
#undef QKPV

    lA += __shfl_xor(lA, 16);
    lA += __shfl_xor(lA, 32);
    lB += __shfl_xor(lB, 16);
    lB += __shfl_xor(lB, 32);
    float invA = 1.0f / lA;
    float invB = 1.0f / lB;

    for (int r = 0; r < 4; r++) {
        int src = (lane & 48) | (quad * 4 + r);
        float invAr = __shfl(invA, src);
        float invBr = __shfl(invB, src);
        int rowA = qblk * 128 + wave * 32 + quad * 4 + r;
        for (int n = 0; n < 4; n++) {
            X[((size_t)b * 2048 + rowA) * 1024 + h * 64 + n * 16 + lm] = f2bf(oA[n][r] * invAr);
            X[((size_t)b * 2048 + rowA + 16) * 1024 + h * 64 + n * 16 + lm] = f2bf(oB[n][r] * invBr);
        }
    }
}

// ---------------------------------------------------------------------------
extern "C" void kernel_launch(void* const* d_in, const int* in_sizes, int n_in,
                              void* d_out, int out_size, void* d_ws, size_t ws_size,
                              hipStream_t stream)
{
    const float* q  = (const float*)d_in[0];
    const float* k  = (const float*)d_in[1];
    const float* v  = (const float*)d_in[2];
    const float* Wq = (const float*)d_in[3];
    const float* bq = (const float*)d_in[4];
    const float* Wk = (const float*)d_in[5];
    const float* bk = (const float*)d_in[6];
    const float* Wv = (const float*)d_in[7];
    const float* bv = (const float*)d_in[8];
    const float* Wo = (const float*)d_in[9];
    const float* bo = (const float*)d_in[10];

    // 40 MB ws layout, sequential aliasing:
    //  0- 4M: WqT,WkT,WvT,WoT (1M elems each)
    //  4- 8M: qbf -> Kh | 8-12M: kbf -> VhT | 12-16M: vbf -> X | 16-20M: Qh
    unsigned short* ws  = (unsigned short*)d_ws;
    const unsigned int M1 = 1u << 20;
    unsigned short* WqT = ws;
    unsigned short* WkT = ws + M1;
    unsigned short* WvT = ws + 2 * M1;
    unsigned short* WoT = ws + 3 * M1;
    unsigned short* qbf = ws + 4 * M1;
    unsigned short* kbf = ws + 8 * M1;
    unsigned short* vbf = ws + 12 * M1;
    unsigned short* Qh  = ws + 16 * M1;
    unsigned short* Kh  = ws + 4 * M1;    // over dead qbf
    unsigned short* VhT = ws + 8 * M1;    // over dead kbf
    unsigned short* X   = ws + 12 * M1;   // over dead vbf

    prep<<<dim3(7168), 256, 0, stream>>>(q, k, v, qbf, kbf, vbf,
                                         Wq, Wk, Wv, Wo, WqT, WkT, WvT, WoT);
    qkv_gemm<<<dim3(32, 8, 3), 256, 0, stream>>>(qbf, kbf, vbf, WqT, WkT, WvT,
                                                 bq, bk, bv, Qh, Kh, VhT);
    attn_kernel<<<dim3(512), 256, 0, stream>>>(Qh, Kh, VhT, X);
    out_gemm<<<dim3(32, 16), 256, 0, stream>>>(X, WoT, bo, (float*)d_out);
}